// Round 9
// baseline (175.982 us; speedup 1.0000x reference)
//
#include <hip/hip_runtime.h>

// MSA conv2d-like QK correlation. B=8, C=128, H=W=128, fp32.
// out[b, i*3+j, h, w] = sum_c Q[b,c,h,w] * K[b,c,h+i-1,w+j-1]  (zero-padded)
//
// Round 9: INSTRUMENT ROUND. Six conv structures (R2-R8: scalar, float4,
// 4x waves, async global_load_lds pipeline, dense 1024-thr strips) ALL pin
// at 128MB-compulsory / ~55us = ~2.3 TB/s read rate, invariant to pattern,
// occupancy (9-35%), VMEM instr count (2.5x), and HBM-vs-L3 mix. Before
// accepting that as the wall, run an unconfounded pure-stream probe in the
// same launch: grid-stride sequential float4 sweep of Q+K at full occupancy,
// checksum to ws (not DCE-able). Probe fast (>=5TB/s) -> c-stride jumps are
// the killer, rebuild conv around sequential planes. Probe ~2.3TB/s ->
// compulsory-byte cap confirmed -> conv ~55us is the roofline.
// Conv = R4 form (best known: 53us, CSPLIT=4 partials + reduce).

#define Bn 8
#define Cn 128
#define Hn 128
#define Wn 128
#define HWn (Hn * Wn)
#define CSPLIT 4
#define CCHUNK (Cn / CSPLIT)
#define OUTN (Bn * 9 * HWn)        // 1179648 output elements
#define NELEM (Bn * Cn * HWn)      // 16777216 elements per input array
#define PROBE_BLOCKS 2048
#define PROBE_THREADS (PROBE_BLOCKS * 256)  // 524288; NELEM/4/THREADS = 8

// ---------------- probe: pure sequential read of Q and K ----------------
__global__ __launch_bounds__(256) void probe_read(
    const float4* __restrict__ A, const float4* __restrict__ B4,
    float* __restrict__ sink) {
  const int tid = blockIdx.x * 256 + threadIdx.x;  // 0..524287
  float s = 0.f;
#pragma unroll
  for (int i = 0; i < 8; ++i) {
    const float4 a = A[(size_t)i * PROBE_THREADS + tid];
    s += a.x + a.y + a.z + a.w;
  }
#pragma unroll
  for (int i = 0; i < 8; ++i) {
    const float4 b = B4[(size_t)i * PROBE_THREADS + tid];
    s += b.x + b.y + b.z + b.w;
  }
#pragma unroll
  for (int off = 32; off; off >>= 1) s += __shfl_down(s, off, 64);
  if ((threadIdx.x & 63) == 0)
    sink[blockIdx.x * 4 + (threadIdx.x >> 6)] = s;
}

// ---------------- conv (R4 form, known 53us) ----------------
template <bool ATOMIC>
__global__ __launch_bounds__(256) void msa_conv_v4(
    const float* __restrict__ Q, const float* __restrict__ K,
    float* __restrict__ dst) {
  const int tid  = threadIdx.x;
  const int lane = tid & 63;
  const int wq   = lane & 31;
  const int rl   = lane >> 5;
  const int wv   = tid >> 6;
  const int h0   = blockIdx.x * 8;
  const int r    = h0 + wv * 2 + rl;
  const int b    = blockIdx.y;
  const int cs   = blockIdx.z;
  const int w0   = wq * 4;

  const int rm = (r > 0) ? r - 1 : r + 1;
  const int rp = (r < Hn - 1) ? r + 1 : r - 1;

  const size_t base = ((size_t)b * Cn + (size_t)cs * CCHUNK) * HWn;
  const float* qp = Q + base + (size_t)r  * Wn + w0;
  const float* mp = K + base + (size_t)rm * Wn + w0;
  const float* zp = K + base + (size_t)r  * Wn + w0;
  const float* pp = K + base + (size_t)rp * Wn + w0;

  float acc[9][4] = {};

#define ACC4(t, s0, s1, s2, s3) \
  acc[t][0] += q4.x * (s0);     \
  acc[t][1] += q4.y * (s1);     \
  acc[t][2] += q4.z * (s2);     \
  acc[t][3] += q4.w * (s3);

#pragma unroll 2
  for (int c = 0; c < CCHUNK; ++c) {
    const float4 q4 = *(const float4*)qp;
    const float4 m4 = *(const float4*)mp;
    const float4 z4 = *(const float4*)zp;
    const float4 p4 = *(const float4*)pp;
    const float mL = __shfl_up(m4.w, 1, 64);
    const float zL = __shfl_up(z4.w, 1, 64);
    const float pL = __shfl_up(p4.w, 1, 64);
    const float mR = __shfl_down(m4.x, 1, 64);
    const float zR = __shfl_down(z4.x, 1, 64);
    const float pR = __shfl_down(p4.x, 1, 64);

    ACC4(0, mL,   m4.x, m4.y, m4.z)
    ACC4(1, m4.x, m4.y, m4.z, m4.w)
    ACC4(2, m4.y, m4.z, m4.w, mR)
    ACC4(3, zL,   z4.x, z4.y, z4.z)
    ACC4(4, z4.x, z4.y, z4.z, z4.w)
    ACC4(5, z4.y, z4.z, z4.w, zR)
    ACC4(6, pL,   p4.x, p4.y, p4.z)
    ACC4(7, p4.x, p4.y, p4.z, p4.w)
    ACC4(8, p4.y, p4.z, p4.w, pR)

    qp += HWn; mp += HWn; zp += HWn; pp += HWn;
  }
#undef ACC4

  if (wq == 0)  { acc[0][0] = 0.f; acc[3][0] = 0.f; acc[6][0] = 0.f; }
  if (wq == 31) { acc[2][3] = 0.f; acc[5][3] = 0.f; acc[8][3] = 0.f; }
  if (r == 0) {
#pragma unroll
    for (int t = 0; t < 3; ++t)
#pragma unroll
      for (int k = 0; k < 4; ++k) acc[t][k] = 0.f;
  }
  if (r == Hn - 1) {
#pragma unroll
    for (int t = 6; t < 9; ++t)
#pragma unroll
      for (int k = 0; k < 4; ++k) acc[t][k] = 0.f;
  }

  const size_t o = (size_t)b * 9 * HWn + (size_t)r * Wn + w0;
  if (ATOMIC) {
#pragma unroll
    for (int t = 0; t < 9; ++t)
#pragma unroll
      for (int k = 0; k < 4; ++k)
        atomicAdd(dst + o + (size_t)t * HWn + k, acc[t][k]);
  } else {
    float* p = dst + (size_t)cs * OUTN + o;
#pragma unroll
    for (int t = 0; t < 9; ++t)
      *(float4*)(p + (size_t)t * HWn) =
          make_float4(acc[t][0], acc[t][1], acc[t][2], acc[t][3]);
  }
}

__global__ __launch_bounds__(256) void msa_reduce4(
    const float* __restrict__ part, float* __restrict__ out) {
  const int i = blockIdx.x * 256 + threadIdx.x;
  const int n4 = OUTN / 4;
  const float4* p = (const float4*)part;
  float4 s0 = p[i];
  float4 s1 = p[n4 + i];
  float4 s2 = p[2 * n4 + i];
  float4 s3 = p[3 * n4 + i];
  float4 r;
  r.x = (s0.x + s1.x) + (s2.x + s3.x);
  r.y = (s0.y + s1.y) + (s2.y + s3.y);
  r.z = (s0.z + s1.z) + (s2.z + s3.z);
  r.w = (s0.w + s1.w) + (s2.w + s3.w);
  ((float4*)out)[i] = r;
}

__global__ __launch_bounds__(256) void msa_zero(float* __restrict__ out) {
  const int i = blockIdx.x * 256 + threadIdx.x;
  ((float4*)out)[i] = make_float4(0.f, 0.f, 0.f, 0.f);
}

extern "C" void kernel_launch(void* const* d_in, const int* in_sizes, int n_in,
                              void* d_out, int out_size, void* d_ws,
                              size_t ws_size, hipStream_t stream) {
  const float* Q = (const float*)d_in[0];
  const float* K = (const float*)d_in[1];
  float* out = (float*)d_out;

  const size_t part_elems = (size_t)CSPLIT * OUTN;          // 18.9 MB
  const size_t sink_elems = (size_t)PROBE_BLOCKS * 4;       // 32 KB
  const bool have_part = ws_size >= (part_elems + sink_elems) * sizeof(float);
  const bool have_sink = ws_size >= sink_elems * sizeof(float);

  // Probe first: pure sequential read of Q and K, checksum into ws.
  if (have_sink) {
    float* sink = (float*)d_ws +
                  (have_part ? part_elems : 0);
    probe_read<<<PROBE_BLOCKS, 256, 0, stream>>>(
        (const float4*)Q, (const float4*)K, sink);
  }

  dim3 block(256);
  dim3 grid(Hn / 8, Bn, CSPLIT);

  if (have_part) {
    float* part = (float*)d_ws;
    msa_conv_v4<false><<<grid, block, 0, stream>>>(Q, K, part);
    msa_reduce4<<<OUTN / 4 / 256, 256, 0, stream>>>(part, out);
  } else {
    msa_zero<<<OUTN / 4 / 256, 256, 0, stream>>>(out);
    msa_conv_v4<true><<<grid, block, 0, stream>>>(Q, K, out);
  }
}